// Round 10
// baseline (1665.914 us; speedup 1.0000x reference)
//
#include <hip/hip_runtime.h>
#include <hip/hip_bf16.h>
#include <cmath>

#define NN 100000   // nodes
#define EE 600000   // edges
#define BB 512      // graphs
#define LL 10       // labels
// H=128; L1 256->512, L2 512->256, L3 256->128, L4 128->128, L5 128->10 (col-picked)

typedef __attribute__((ext_vector_type(8))) short  bf16x8;
typedef __attribute__((ext_vector_type(4))) float  f32x4;
typedef unsigned int uint;
typedef unsigned short ushort;

// Fast elu (R13): __expf instead of libm expm1f; error ~2^-17, same order as
// the hi/lo bf16 representation. absmax tripwire >1e-3 => revert.
__device__ __forceinline__ float elu_f(float x){ return x > 0.f ? x : __expf(x) - 1.f; }

__device__ __forceinline__ ushort bf16_rne(float f){
  uint u = __float_as_uint(f);
  return (ushort)((u + 0x7FFFu + ((u >> 16) & 1u)) >> 16);
}

__device__ __forceinline__ f32x4 MFMA(bf16x8 a, bf16x8 b, f32x4 c){
  return __builtin_amdgcn_mfma_f32_16x16x32_bf16(a, b, c, 0, 0, 0);
}

// Monotone float<->uint encoding for atomic max/min on floats
__device__ __forceinline__ unsigned enc_f(float f){
  unsigned u = __float_as_uint(f);
  return (u & 0x80000000u) ? ~u : (u | 0x80000000u);
}
__device__ __forceinline__ float dec_f(unsigned u){
  return (u & 0x80000000u) ? __uint_as_float(u ^ 0x80000000u) : __uint_as_float(~u);
}
#define ENC_NEG_INF 0x007FFFFFu

// sA row stride (R13): 260 ushorts = 520 B -> 2-bank shift/row; conflict-free
// for the ds_read2_b64-lowered A-frag reads (every bank exactly 4 requests).
#define AROW 260

// ---------------------------------------------------------------------------
// kReps: repsF[n] = 512B row: [hi bf16 k=0..127][lo bf16 k=0..127].
// ---------------------------------------------------------------------------
__global__ __launch_bounds__(256) void kReps(const float* __restrict__ r0,
                                             const float* __restrict__ r1,
                                             ushort* __restrict__ repsF){
  int gid = blockIdx.x*256 + threadIdx.x;          // N*16 threads
  int n = gid >> 4, k8 = gid & 15;
  const float4* a = (const float4*)(r0 + (size_t)n*128 + k8*8);
  const float4* b = (const float4*)(r1 + (size_t)n*128 + k8*8);
  float4 x0 = a[0], x1 = a[1], y0 = b[0], y1 = b[1];
  float d[8] = {x0.x-y0.x, x0.y-y0.y, x0.z-y0.z, x0.w-y0.w,
                x1.x-y1.x, x1.y-y1.y, x1.z-y1.z, x1.w-y1.w};
  ushort hi[8], lo[8];
  #pragma unroll
  for (int j=0;j<8;++j){
    hi[j] = bf16_rne(d[j]);
    float fh = __uint_as_float(((uint)hi[j])<<16);
    lo[j] = bf16_rne(d[j] - fh);
  }
  ushort* dh = repsF + (size_t)n*256 + k8*8;
  ushort* dl = dh + 128;
  #pragma unroll
  for (int j=0;j<8;++j){ dh[j] = hi[j]; dl[j] = lo[j]; }
}

// ---------------------------------------------------------------------------
// kPrepW: weight [K][N] fp32 -> MFMA-fragment bf16 hi/lo:
//   dst[part][kt][nt][lane][j] with k = kt*32+(l>>4)*8+j, n = nt*16+(l&15).
// ---------------------------------------------------------------------------
__global__ __launch_bounds__(256) void kPrepW(const float* __restrict__ W, int N,
                                              int KT, int NT, ushort* __restrict__ dst){
  int gid = blockIdx.x*256 + threadIdx.x;
  int total = KT*NT*64;
  if (gid >= total) return;
  int l = gid & 63, tile = gid >> 6;
  int kt = tile / NT, nt = tile % NT;
  int kbase = kt*32 + (l>>4)*8;
  int n = nt*16 + (l&15);
  int partStride = KT*NT*512;
  int base = tile*512 + l*8;
  #pragma unroll
  for (int j=0;j<8;++j){
    float f = W[(size_t)(kbase+j)*N + n];
    ushort h = bf16_rne(f);
    float fh = __uint_as_float(((uint)h)<<16);
    dst[base + j] = h;
    dst[partStride + base + j] = bf16_rne(f - fh);
  }
}

// ---------------------------------------------------------------------------
// LDS transpose helpers (region = [part(2)][m(32)][col(64) pad 68] ushorts).
// Region = 4352 ushorts (8704 B); part offset 2176 ushorts = 1088 uints.
// ---------------------------------------------------------------------------
template<int NTILES>
__device__ __forceinline__ void xposeN(ushort* sT, const f32x4* Cg,
                                       const float* __restrict__ biasPtr,
                                       bool doElu, int l){
  const int quad = l >> 4, r16 = l & 15;
  uint* ldsu = (uint*)sT;
  #pragma unroll
  for (int i = 0; i < NTILES; ++i){
    float bv = biasPtr[i*16 + r16];
    #pragma unroll
    for (int mtl = 0; mtl < 2; ++mtl){
      f32x4 v = Cg[i*2 + mtl];
      ushort hi[4], lo[4];
      #pragma unroll
      for (int r = 0; r < 4; ++r){
        float f = v[r] + bv;
        if (doElu) f = elu_f(f);
        hi[r] = bf16_rne(f);
        float fh = __uint_as_float(((uint)hi[r]) << 16);
        lo[r] = bf16_rne(f - fh);
      }
      uint v01h = (uint)hi[0] | ((uint)hi[1]<<16);
      uint v23h = (uint)hi[2] | ((uint)hi[3]<<16);
      uint v01l = (uint)lo[0] | ((uint)lo[1]<<16);
      uint v23l = (uint)lo[2] | ((uint)lo[3]<<16);
      uint t01h = __shfl_xor(v01h,1), t23h = __shfl_xor(v23h,1);
      uint t01l = __shfl_xor(v01l,1), t23l = __shfl_xor(v23l,1);
      int c2 = (i*16 + (r16 & ~1)) >> 1;      // uint col index
      int m0 = mtl*16 + quad*4;
      if (!(l & 1)){
        ldsu[(m0+0)*34 + c2]        = (v01h & 0xFFFFu) | (t01h << 16);
        ldsu[(m0+1)*34 + c2]        = (v01h >> 16) | (t01h & 0xFFFF0000u);
        ldsu[1088 + (m0+0)*34 + c2] = (v01l & 0xFFFFu) | (t01l << 16);
        ldsu[1088 + (m0+1)*34 + c2] = (v01l >> 16) | (t01l & 0xFFFF0000u);
      } else {
        ldsu[(m0+2)*34 + c2]        = (t23h & 0xFFFFu) | (v23h << 16);
        ldsu[(m0+3)*34 + c2]        = (t23h >> 16) | (v23h & 0xFFFF0000u);
        ldsu[1088 + (m0+2)*34 + c2] = (t23l & 0xFFFFu) | (v23l << 16);
        ldsu[1088 + (m0+3)*34 + c2] = (t23l >> 16) | (v23l & 0xFFFF0000u);
      }
    }
  }
}

__device__ __forceinline__ bf16x8 readA(const ushort* region, int part, int m, int colBase){
  union { uint2 u[2]; bf16x8 v; } cvt;
  const ushort* p = region + part*2176 + m*68 + colBase;
  cvt.u[0] = *(const uint2*)p;
  cvt.u[1] = *(const uint2*)(p + 4);
  return cvt.v;
}

// 8B-aligned bf16x8 load from sA (row stride 520 B: odd rows only 8B-aligned).
__device__ __forceinline__ bf16x8 loadA8(const ushort* p){
  union { uint2 u[2]; bf16x8 v; } cvt;
  cvt.u[0] = *(const uint2*)p;
  cvt.u[1] = *(const uint2*)(p + 4);
  return cvt.v;
}

// ---------------------------------------------------------------------------
// R15: L1 split into two K-half passes so sA holds only 32 rows at a time
// (src rows for hk 0-3, then dst rows for hk 4-7). C1 partials for all 8
// slices persist in registers across the passes (C1s[8][2], statically
// indexed via full unroll -- rule #20). hk order per accumulator is 0..7
// sequential, identical to R13 -> bit-identical output.
// produceHalf: 4 hk-steps of slice sl from sA rows 0..31.
// ---------------------------------------------------------------------------
__device__ __forceinline__ void produceHalf(int sl, int w, int l, int quad, int r16,
    const ushort* sA, int hkBase,
    const ushort* __restrict__ W1F, f32x4 (&C1)[2]){
  #pragma unroll
  for (int hh = 0; hh < 4; ++hh){
    const int hk = hkBase + hh;
    const int ko = hh*32 + quad*8;
    const ushort* r0p = sA + r16*AROW + ko;
    const ushort* r1p = sA + (16 + r16)*AROW + ko;
    bf16x8 Ah0 = loadA8(r0p);
    bf16x8 Al0 = loadA8(r0p + 128);
    bf16x8 Ah1 = loadA8(r1p);
    bf16x8 Al1 = loadA8(r1p + 128);
    const bf16x8* WfH = (const bf16x8*)W1F + ((size_t)hk*32 + sl*4 + w)*64 + l;
    const bf16x8* WfL = WfH + 8*32*64;
    bf16x8 Bh = WfH[0], Bl = WfL[0];
    C1[0] = MFMA(Ah0, Bh, C1[0]); C1[1] = MFMA(Ah1, Bh, C1[1]);
    C1[0] = MFMA(Ah0, Bl, C1[0]); C1[1] = MFMA(Ah1, Bl, C1[1]);
    C1[0] = MFMA(Al0, Bh, C1[0]); C1[1] = MFMA(Al1, Bh, C1[1]);
  }
}

__device__ __forceinline__ void consumeSlice(int s, int w, int l, int quad, int r16,
    const ushort* buf, const ushort* __restrict__ W2F, f32x4 (&C2q)[8]){
  #pragma unroll
  for (int j2 = 0; j2 < 2; ++j2){
    int colBase = j2*32 + quad*8;
    bf16x8 Ah[2], Al[2];
    #pragma unroll
    for (int mtl = 0; mtl < 2; ++mtl){
      int m = mtl*16 + r16;
      Ah[mtl] = readA(buf, 0, m, colBase);
      Al[mtl] = readA(buf, 1, m, colBase);
    }
    const int kt = s*2 + j2;                       // W2 k-tile (KT=16)
    const bf16x8* WfH = (const bf16x8*)W2F + ((size_t)kt*16 + w*4)*64 + l;
    const bf16x8* WfL = WfH + 16*16*64;
    #pragma unroll
    for (int j = 0; j < 4; ++j){
      bf16x8 Bh = WfH[j*64], Bl = WfL[j*64];
      f32x4 c0 = C2q[j*2], c1 = C2q[j*2+1];
      c0 = MFMA(Ah[0], Bh, c0); c1 = MFMA(Ah[1], Bh, c1);
      c0 = MFMA(Ah[0], Bl, c0); c1 = MFMA(Ah[1], Bl, c1);
      c0 = MFMA(Al[0], Bh, c0); c1 = MFMA(Al[1], Bh, c1);
      C2q[j*2] = c0; C2q[j*2+1] = c1;
    }
  }
}

// ---------------------------------------------------------------------------
// kMLP R15: R13 structure (verified 1430 us; R14 pipeline reverted) with the
// L1 loop split into two K-half passes. LDS 51.7 -> ~35.7 KB => 4 blocks/CU
// (16 waves/CU, +33% latency-hiding TLP against the L2 B-stream).
// A gather happens twice (src rows, then dst rows) -- still coalesced, still
// tiny vs the old per-slice re-read.
// ---------------------------------------------------------------------------
__global__ __launch_bounds__(256, 4) void kMLP(
    const ushort* __restrict__ repsF,
    const ushort* __restrict__ W1F, const ushort* __restrict__ W2F,
    const ushort* __restrict__ W3F, const ushort* __restrict__ W4F,
    const float* __restrict__ b1, const float* __restrict__ b2,
    const float* __restrict__ b3, const float* __restrict__ b4,
    const float* __restrict__ W5, const float* __restrict__ b5,
    const int* __restrict__ edge_index, const int* __restrict__ batch,
    const int* __restrict__ y,
    float* __restrict__ scores, int* __restrict__ ebatch)
{
  __shared__ __align__(16) ushort sReg01[2*4352];  // regions 0,1 (17408 B)
  __shared__ __align__(16) ushort sA[2*4352];      // 32 A rows (8320 used of
                                                   // 8704); aliases regions
                                                   // 2,3 for L3 h2 staging
  __shared__ int sTy[32];
  __shared__ int sNode[64];
  __shared__ float sRed[4][32];

  const int tid = threadIdx.x;
  const int w = tid >> 6;                        // wave 0..3
  const int l = tid & 63;
  const int quad = l >> 4, r16 = l & 15;
  const int e0 = blockIdx.x * 32;

  if (tid < 32){
    int s = edge_index[e0 + tid];
    int d = edge_index[EE + e0 + tid];
    sNode[tid] = s;
    sNode[32 + tid] = d;
    int eb = batch[s];
    ebatch[e0 + tid] = eb;
    sTy[tid] = y[eb];
  }
  __syncthreads();

  // ---- stage SRC rows (32 x 512 B, coalesced) ----
  #pragma unroll
  for (int k = 0; k < 4; ++k){
    int c = tid + k*256;                         // 0..1023 16B-chunks
    int row = c >> 5, col = c & 31;              // 32 chunks per row
    const ushort* src = repsF + (size_t)sNode[row]*256 + col*8;
    uint4 v = *(const uint4*)src;
    ushort* dst = sA + row*AROW + col*8;
    *(uint2*)dst        = make_uint2(v.x, v.y);
    *(uint2*)(dst + 4)  = make_uint2(v.z, v.w);
  }
  __syncthreads();

  // ---- L1 pass 1: hk 0..3 (src K-half) for ALL 8 slices -> C1s ----
  f32x4 C1s[8][2];
  #pragma unroll
  for (int s=0;s<8;++s){ C1s[s][0] = (f32x4)0.f; C1s[s][1] = (f32x4)0.f; }
  #pragma unroll
  for (int s = 0; s < 8; ++s)
    produceHalf(s, w, l, quad, r16, sA, 0, W1F, C1s[s]);

  __syncthreads();   // all waves done reading src rows

  // ---- restage DST rows over sA ----
  #pragma unroll
  for (int k = 0; k < 4; ++k){
    int c = tid + k*256;
    int row = c >> 5, col = c & 31;
    const ushort* src = repsF + (size_t)sNode[32 + row]*256 + col*8;
    uint4 v = *(const uint4*)src;
    ushort* dst = sA + row*AROW + col*8;
    *(uint2*)dst        = make_uint2(v.x, v.y);
    *(uint2*)(dst + 4)  = make_uint2(v.z, v.w);
  }
  __syncthreads();

  // ---- L1 pass 2 + L2: finish slice (hk 4..7), xpose, consume (dbuf'd) ----
  f32x4 C2q[8];                    // 4 local n-tiles x 2 m-tiles (32 regs)
  #pragma unroll
  for (int i=0;i<8;++i) C2q[i] = (f32x4)0.f;

  produceHalf(0, w, l, quad, r16, sA, 4, W1F, C1s[0]);
  xposeN<1>(sReg01 + w*16, C1s[0], b1 + w*16, true, l);
  __syncthreads();
  #pragma unroll
  for (int s = 0; s < 7; ++s){
    produceHalf(s+1, w, l, quad, r16, sA, 4, W1F, C1s[s+1]);
    xposeN<1>(sReg01 + ((s+1)&1)*4352 + w*16, C1s[s+1],
              b1 + (s+1)*64 + w*16, true, l);
    consumeSlice(s, w, l, quad, r16, sReg01 + (s&1)*4352, W2F, C2q);
    __syncthreads();
  }
  consumeSlice(7, w, l, quad, r16, sReg01 + 4352, W2F, C2q);
  __syncthreads();

  // ---- h2 staging: wave w -> region w (cols w*64..), elu+b2 ----
  // regions 2,3 alias sA (A dead after the slice loop).
  ushort* regW = (w < 2) ? (sReg01 + w*4352) : (sA + (w-2)*4352);
  xposeN<4>(regW, C2q, b2 + w*64, true, l);
  __syncthreads();

  // ---- layer 3: K=256 from h2 regions; wave w computes h3 cols w*32.. ----
  f32x4 C3q[4];
  #pragma unroll
  for (int i=0;i<4;++i) C3q[i] = (f32x4)0.f;
  #pragma unroll
  for (int kt = 0; kt < 8; ++kt){
    int rw = kt >> 1;
    const ushort* reg = (rw < 2) ? (sReg01 + rw*4352) : (sA + (rw-2)*4352);
    int colBase = (kt & 1)*32 + quad*8;
    bf16x8 Ah[2], Al[2];
    #pragma unroll
    for (int mtl = 0; mtl < 2; ++mtl){
      int m = mtl*16 + r16;
      Ah[mtl] = readA(reg, 0, m, colBase);
      Al[mtl] = readA(reg, 1, m, colBase);
    }
    const bf16x8* WfH = (const bf16x8*)W3F + ((size_t)kt*8 + w*2)*64 + l;
    const bf16x8* WfL = WfH + 8*8*64;
    #pragma unroll
    for (int j = 0; j < 2; ++j){
      bf16x8 Bh = WfH[j*64], Bl = WfL[j*64];
      f32x4 c0 = C3q[j*2], c1 = C3q[j*2+1];
      c0 = MFMA(Ah[0], Bh, c0); c1 = MFMA(Ah[1], Bh, c1);
      c0 = MFMA(Ah[0], Bl, c0); c1 = MFMA(Ah[1], Bl, c1);
      c0 = MFMA(Al[0], Bh, c0); c1 = MFMA(Al[1], Bh, c1);
      C3q[j*2] = c0; C3q[j*2+1] = c1;
    }
  }
  __syncthreads();   // all waves done reading h2 regions

  // ---- h3 staging (b3, NO elu): wave w -> region (w>>1), col (w&1)*32 ----
  xposeN<2>(sReg01 + (w>>1)*4352 + (w&1)*32, C3q, b3 + w*32, false, l);
  __syncthreads();

  // ---- layer 4: K=128 from h3 (regions 0-1); wave w -> h4 cols w*32.. ----
  f32x4 C4q[4];
  #pragma unroll
  for (int i=0;i<4;++i) C4q[i] = (f32x4)0.f;
  #pragma unroll
  for (int kt = 0; kt < 4; ++kt){
    const ushort* reg = sReg01 + (kt>>1)*4352;
    int colBase = (kt & 1)*32 + quad*8;
    bf16x8 Ah[2], Al[2];
    #pragma unroll
    for (int mtl = 0; mtl < 2; ++mtl){
      int m = mtl*16 + r16;
      Ah[mtl] = readA(reg, 0, m, colBase);
      Al[mtl] = readA(reg, 1, m, colBase);
    }
    const bf16x8* WfH = (const bf16x8*)W4F + ((size_t)kt*8 + w*2)*64 + l;
    const bf16x8* WfL = WfH + 4*8*64;
    #pragma unroll
    for (int j = 0; j < 2; ++j){
      bf16x8 Bh = WfH[j*64], Bl = WfL[j*64];
      f32x4 c0 = C4q[j*2], c1 = C4q[j*2+1];
      c0 = MFMA(Ah[0], Bh, c0); c1 = MFMA(Ah[1], Bh, c1);
      c0 = MFMA(Ah[0], Bl, c0); c1 = MFMA(Ah[1], Bl, c1);
      c0 = MFMA(Al[0], Bh, c0); c1 = MFMA(Al[1], Bh, c1);
      C4q[j*2] = c0; C4q[j*2+1] = c1;
    }
  }

  // ---- layer 5: per-wave partial dot over its 32 h4 cols, LDS reduce ----
  int tvals[2][4];
  #pragma unroll
  for (int mtl=0;mtl<2;++mtl)
    #pragma unroll
    for (int r=0;r<4;++r) tvals[mtl][r] = sTy[mtl*16 + quad*4 + r];

  float p[2][4] = {{0.f,0.f,0.f,0.f},{0.f,0.f,0.f,0.f}};
  #pragma unroll
  for (int j = 0; j < 2; ++j){
    int n4 = (w*2 + j)*16 + r16;
    float bv = b4[n4];
    const float* w5r = W5 + n4*LL;
    #pragma unroll
    for (int mtl = 0; mtl < 2; ++mtl){
      f32x4 c = C4q[j*2+mtl];
      #pragma unroll
      for (int r=0;r<4;++r)
        p[mtl][r] += elu_f(c[r] + bv) * w5r[tvals[mtl][r]];
    }
  }
  #pragma unroll
  for (int d = 8; d >= 1; d >>= 1){
    #pragma unroll
    for (int mtl=0;mtl<2;++mtl)
      #pragma unroll
      for (int r=0;r<4;++r)
        p[mtl][r] += __shfl_down(p[mtl][r], d, 16);
  }
  if (r16 == 0){
    #pragma unroll
    for (int mtl=0;mtl<2;++mtl)
      #pragma unroll
      for (int r=0;r<4;++r){
        int m = mtl*16 + quad*4 + r;
        sRed[w][m] = p[mtl][r];
      }
  }
  __syncthreads();
  if (tid < 32){
    float s = sRed[0][tid] + sRed[1][tid] + sRed[2][tid] + sRed[3][tid];
    scores[e0 + tid] = s + b5[sTy[tid]];
  }
}

// ---------------------------------------------------------------------------
// Segment softmax / argmax passes (unchanged, verified)
// ---------------------------------------------------------------------------
__global__ void kInitSeg(unsigned* segmax, float* segsum, unsigned* gmax, int* gact){
  int b = blockIdx.x*blockDim.x + threadIdx.x;
  if (b < BB){ segmax[b] = ENC_NEG_INF; segsum[b] = 0.f; gmax[b] = ENC_NEG_INF; gact[b] = 0x7FFFFFFF; }
}

__global__ __launch_bounds__(256) void kSegMax(const float* __restrict__ scores,
                                               const int* __restrict__ eb,
                                               unsigned* __restrict__ segmax){
  __shared__ unsigned l[BB];
  for (int b = threadIdx.x; b < BB; b += 256) l[b] = 0u;
  __syncthreads();
  for (int e = blockIdx.x*256 + threadIdx.x; e < EE; e += gridDim.x*256)
    atomicMax(&l[eb[e]], enc_f(scores[e]));
  __syncthreads();
  for (int b = threadIdx.x; b < BB; b += 256)
    if (l[b]) atomicMax(&segmax[b], l[b]);
}

__global__ __launch_bounds__(256) void kExpSum(const float* __restrict__ scores,
                                               const int* __restrict__ eb,
                                               const unsigned* __restrict__ segmax,
                                               float* __restrict__ segsum,
                                               float* __restrict__ outprobs){
  __shared__ float l[BB];
  for (int b = threadIdx.x; b < BB; b += 256) l[b] = 0.f;
  __syncthreads();
  for (int e = blockIdx.x*256 + threadIdx.x; e < EE; e += gridDim.x*256){
    int b = eb[e];
    float ex = expf(scores[e] - dec_f(segmax[b]));
    outprobs[e] = ex;
    atomicAdd(&l[b], ex);
  }
  __syncthreads();
  for (int b = threadIdx.x; b < BB; b += 256)
    if (l[b] != 0.f) atomicAdd(&segsum[b], l[b]);
}

__global__ __launch_bounds__(256) void kProbMax(float* __restrict__ outprobs,
                                                const int* __restrict__ eb,
                                                const float* __restrict__ segsum,
                                                unsigned* __restrict__ gmax){
  __shared__ unsigned l[BB];
  for (int b = threadIdx.x; b < BB; b += 256) l[b] = 0u;
  __syncthreads();
  for (int e = blockIdx.x*256 + threadIdx.x; e < EE; e += gridDim.x*256){
    int b = eb[e];
    float p = outprobs[e] / segsum[b];
    outprobs[e] = p;
    atomicMax(&l[b], enc_f(p));
  }
  __syncthreads();
  for (int b = threadIdx.x; b < BB; b += 256)
    if (l[b]) atomicMax(&gmax[b], l[b]);
}

__global__ __launch_bounds__(256) void kArgMin(const float* __restrict__ outprobs,
                                               const int* __restrict__ eb,
                                               const unsigned* __restrict__ gmax,
                                               int* __restrict__ gact){
  __shared__ int l[BB];
  for (int b = threadIdx.x; b < BB; b += 256) l[b] = 0x7FFFFFFF;
  __syncthreads();
  for (int e = blockIdx.x*256 + threadIdx.x; e < EE; e += gridDim.x*256){
    int b = eb[e];
    if (enc_f(outprobs[e]) == gmax[b]) atomicMin(&l[b], e);
  }
  __syncthreads();
  for (int b = threadIdx.x; b < BB; b += 256)
    if (l[b] != 0x7FFFFFFF) atomicMin(&gact[b], l[b]);
}

__global__ void kFinal(const unsigned* __restrict__ gmax, const int* __restrict__ gact,
                       float* __restrict__ out){
  int b = threadIdx.x;
  if (b < BB){
    out[EE + b]      = dec_f(gmax[b]);
    out[EE + BB + b] = (float)gact[b];
  }
}

// ---------------------------------------------------------------------------
extern "C" void kernel_launch(void* const* d_in, const int* in_sizes, int n_in,
                              void* d_out, int out_size, void* d_ws, size_t ws_size,
                              hipStream_t stream){
  const float* r0 = (const float*)d_in[0];
  const float* r1 = (const float*)d_in[1];
  const float* W1 = (const float*)d_in[2];
  const float* b1 = (const float*)d_in[3];
  const float* W2 = (const float*)d_in[4];
  const float* b2 = (const float*)d_in[5];
  const float* W3 = (const float*)d_in[6];
  const float* b3 = (const float*)d_in[7];
  const float* W4 = (const float*)d_in[8];
  const float* b4 = (const float*)d_in[9];
  const float* W5 = (const float*)d_in[10];
  const float* b5 = (const float*)d_in[11];
  const int* edge_index = (const int*)d_in[12];
  const int* batch = (const int*)d_in[13];
  const int* y = (const int*)d_in[14];
  float* out = (float*)d_out;

  char* ws = (char*)d_ws;
  size_t off = 0;
  float*    scores = (float*)(ws + off);    off += (size_t)EE*4;
  int*      ebatch = (int*)(ws + off);      off += (size_t)EE*4;
  unsigned* segmax = (unsigned*)(ws + off); off += BB*4;
  float*    segsum = (float*)(ws + off);    off += BB*4;
  unsigned* gmax   = (unsigned*)(ws + off); off += BB*4;
  int*      gact   = (int*)(ws + off);      off += BB*4;
  off = (off + 511) & ~(size_t)511;
  ushort* repsF = (ushort*)(ws + off);      off += (size_t)NN*256*2;   // 51.2 MB
  ushort* W1F   = (ushort*)(ws + off);      off += (size_t)2*8*32*512*2;
  ushort* W2F   = (ushort*)(ws + off);      off += (size_t)2*16*16*512*2;
  ushort* W3F   = (ushort*)(ws + off);      off += (size_t)2*8*8*512*2;
  ushort* W4F   = (ushort*)(ws + off);      off += (size_t)2*4*8*512*2;

  kInitSeg<<<2, 256, 0, stream>>>(segmax, segsum, gmax, gact);
  kReps<<<(NN*16)/256, 256, 0, stream>>>(r0, r1, repsF);
  kPrepW<<<(8*32*64)/256, 256, 0, stream>>>(W1, 512, 8, 32, W1F);
  kPrepW<<<(16*16*64)/256, 256, 0, stream>>>(W2, 256, 16, 16, W2F);
  kPrepW<<<(8*8*64)/256, 256, 0, stream>>>(W3, 128, 8, 8, W3F);
  kPrepW<<<(4*8*64)/256, 256, 0, stream>>>(W4, 128, 4, 8, W4F);

  kMLP<<<EE/32, 256, 0, stream>>>(repsF, W1F, W2F, W3F, W4F,
                                  b1, b2, b3, b4, W5, b5,
                                  edge_index, batch, y, scores, ebatch);

  kSegMax <<<256, 256, 0, stream>>>(scores, ebatch, segmax);
  kExpSum <<<256, 256, 0, stream>>>(scores, ebatch, segmax, segsum, out);
  kProbMax<<<256, 256, 0, stream>>>(out, ebatch, segsum, gmax);
  kArgMin <<<256, 256, 0, stream>>>(out, ebatch, gmax, gact);
  kFinal  <<<1, 512, 0, stream>>>(gmax, gact, out);
}

// Round 11
// 1577.682 us; speedup vs baseline: 1.0559x; 1.0559x over previous
//
#include <hip/hip_runtime.h>
#include <hip/hip_bf16.h>
#include <cmath>

#define NN 100000   // nodes
#define EE 600000   // edges
#define BB 512      // graphs
#define LL 10       // labels
// H=128; L1 256->512, L2 512->256, L3 256->128, L4 128->128, L5 128->10 (col-picked)

typedef __attribute__((ext_vector_type(8))) short  bf16x8;
typedef __attribute__((ext_vector_type(4))) float  f32x4;
typedef unsigned int uint;
typedef unsigned short ushort;

// Fast elu (R13): __expf instead of libm expm1f; error ~2^-17, same order as
// the hi/lo bf16 representation. absmax tripwire >1e-3 => revert.
__device__ __forceinline__ float elu_f(float x){ return x > 0.f ? x : __expf(x) - 1.f; }

__device__ __forceinline__ ushort bf16_rne(float f){
  uint u = __float_as_uint(f);
  return (ushort)((u + 0x7FFFu + ((u >> 16) & 1u)) >> 16);
}

__device__ __forceinline__ f32x4 MFMA(bf16x8 a, bf16x8 b, f32x4 c){
  return __builtin_amdgcn_mfma_f32_16x16x32_bf16(a, b, c, 0, 0, 0);
}

// Monotone float<->uint encoding for atomic max/min on floats
__device__ __forceinline__ unsigned enc_f(float f){
  unsigned u = __float_as_uint(f);
  return (u & 0x80000000u) ? ~u : (u | 0x80000000u);
}
__device__ __forceinline__ float dec_f(unsigned u){
  return (u & 0x80000000u) ? __uint_as_float(u ^ 0x80000000u) : __uint_as_float(~u);
}
#define ENC_NEG_INF 0x007FFFFFu

// sA row stride (R13): 260 ushorts = 520 B -> 2-bank shift/row; conflict-free
// for the ds_read2_b64-lowered A-frag reads (every bank exactly 4 requests).
#define AROW 260

// ---------------------------------------------------------------------------
// kReps: repsF[n] = 512B row: [hi bf16 k=0..127][lo bf16 k=0..127].
// ---------------------------------------------------------------------------
__global__ __launch_bounds__(256) void kReps(const float* __restrict__ r0,
                                             const float* __restrict__ r1,
                                             ushort* __restrict__ repsF){
  int gid = blockIdx.x*256 + threadIdx.x;          // N*16 threads
  int n = gid >> 4, k8 = gid & 15;
  const float4* a = (const float4*)(r0 + (size_t)n*128 + k8*8);
  const float4* b = (const float4*)(r1 + (size_t)n*128 + k8*8);
  float4 x0 = a[0], x1 = a[1], y0 = b[0], y1 = b[1];
  float d[8] = {x0.x-y0.x, x0.y-y0.y, x0.z-y0.z, x0.w-y0.w,
                x1.x-y1.x, x1.y-y1.y, x1.z-y1.z, x1.w-y1.w};
  ushort hi[8], lo[8];
  #pragma unroll
  for (int j=0;j<8;++j){
    hi[j] = bf16_rne(d[j]);
    float fh = __uint_as_float(((uint)hi[j])<<16);
    lo[j] = bf16_rne(d[j] - fh);
  }
  ushort* dh = repsF + (size_t)n*256 + k8*8;
  ushort* dl = dh + 128;
  #pragma unroll
  for (int j=0;j<8;++j){ dh[j] = hi[j]; dl[j] = lo[j]; }
}

// ---------------------------------------------------------------------------
// kPrepW: weight [K][N] fp32 -> MFMA-fragment bf16 hi/lo:
//   dst[part][kt][nt][lane][j] with k = kt*32+(l>>4)*8+j, n = nt*16+(l&15).
// ---------------------------------------------------------------------------
__global__ __launch_bounds__(256) void kPrepW(const float* __restrict__ W, int N,
                                              int KT, int NT, ushort* __restrict__ dst){
  int gid = blockIdx.x*256 + threadIdx.x;
  int total = KT*NT*64;
  if (gid >= total) return;
  int l = gid & 63, tile = gid >> 6;
  int kt = tile / NT, nt = tile % NT;
  int kbase = kt*32 + (l>>4)*8;
  int n = nt*16 + (l&15);
  int partStride = KT*NT*512;
  int base = tile*512 + l*8;
  #pragma unroll
  for (int j=0;j<8;++j){
    float f = W[(size_t)(kbase+j)*N + n];
    ushort h = bf16_rne(f);
    float fh = __uint_as_float(((uint)h)<<16);
    dst[base + j] = h;
    dst[partStride + base + j] = bf16_rne(f - fh);
  }
}

// ---------------------------------------------------------------------------
// LDS transpose helpers (region = [part(2)][m(32)][col(64) pad 68] ushorts).
// Region = 4352 ushorts (8704 B); part offset 2176 ushorts = 1088 uints.
// ---------------------------------------------------------------------------
template<int NTILES>
__device__ __forceinline__ void xposeN(ushort* sT, const f32x4* Cg,
                                       const float* __restrict__ biasPtr,
                                       bool doElu, int l){
  const int quad = l >> 4, r16 = l & 15;
  uint* ldsu = (uint*)sT;
  #pragma unroll
  for (int i = 0; i < NTILES; ++i){
    float bv = biasPtr[i*16 + r16];
    #pragma unroll
    for (int mtl = 0; mtl < 2; ++mtl){
      f32x4 v = Cg[i*2 + mtl];
      ushort hi[4], lo[4];
      #pragma unroll
      for (int r = 0; r < 4; ++r){
        float f = v[r] + bv;
        if (doElu) f = elu_f(f);
        hi[r] = bf16_rne(f);
        float fh = __uint_as_float(((uint)hi[r]) << 16);
        lo[r] = bf16_rne(f - fh);
      }
      uint v01h = (uint)hi[0] | ((uint)hi[1]<<16);
      uint v23h = (uint)hi[2] | ((uint)hi[3]<<16);
      uint v01l = (uint)lo[0] | ((uint)lo[1]<<16);
      uint v23l = (uint)lo[2] | ((uint)lo[3]<<16);
      uint t01h = __shfl_xor(v01h,1), t23h = __shfl_xor(v23h,1);
      uint t01l = __shfl_xor(v01l,1), t23l = __shfl_xor(v23l,1);
      int c2 = (i*16 + (r16 & ~1)) >> 1;      // uint col index
      int m0 = mtl*16 + quad*4;
      if (!(l & 1)){
        ldsu[(m0+0)*34 + c2]        = (v01h & 0xFFFFu) | (t01h << 16);
        ldsu[(m0+1)*34 + c2]        = (v01h >> 16) | (t01h & 0xFFFF0000u);
        ldsu[1088 + (m0+0)*34 + c2] = (v01l & 0xFFFFu) | (t01l << 16);
        ldsu[1088 + (m0+1)*34 + c2] = (v01l >> 16) | (t01l & 0xFFFF0000u);
      } else {
        ldsu[(m0+2)*34 + c2]        = (t23h & 0xFFFFu) | (v23h << 16);
        ldsu[(m0+3)*34 + c2]        = (t23h >> 16) | (v23h & 0xFFFF0000u);
        ldsu[1088 + (m0+2)*34 + c2] = (t23l & 0xFFFFu) | (v23l << 16);
        ldsu[1088 + (m0+3)*34 + c2] = (t23l >> 16) | (v23l & 0xFFFF0000u);
      }
    }
  }
}

__device__ __forceinline__ bf16x8 readA(const ushort* region, int part, int m, int colBase){
  union { uint2 u[2]; bf16x8 v; } cvt;
  const ushort* p = region + part*2176 + m*68 + colBase;
  cvt.u[0] = *(const uint2*)p;
  cvt.u[1] = *(const uint2*)(p + 4);
  return cvt.v;
}

// 8B-aligned bf16x8 load from sA (row stride 520 B: odd rows only 8B-aligned).
__device__ __forceinline__ bf16x8 loadA8(const ushort* p){
  union { uint2 u[2]; bf16x8 v; } cvt;
  cvt.u[0] = *(const uint2*)p;
  cvt.u[1] = *(const uint2*)(p + 4);
  return cvt.v;
}

// ---------------------------------------------------------------------------
// produceHalf: 4 hk-steps (hkBase..hkBase+3) of slice sl from sA rows 0..31.
// hk order per accumulator is 0..7 sequential across the two calls ->
// bit-identical to R13.
// ---------------------------------------------------------------------------
__device__ __forceinline__ void produceHalf(int sl, int w, int l, int quad, int r16,
    const ushort* sA, int hkBase,
    const ushort* __restrict__ W1F, f32x4 (&C1)[2]){
  #pragma unroll
  for (int hh = 0; hh < 4; ++hh){
    const int hk = hkBase + hh;
    const int ko = hh*32 + quad*8;
    const ushort* r0p = sA + r16*AROW + ko;
    const ushort* r1p = sA + (16 + r16)*AROW + ko;
    bf16x8 Ah0 = loadA8(r0p);
    bf16x8 Al0 = loadA8(r0p + 128);
    bf16x8 Ah1 = loadA8(r1p);
    bf16x8 Al1 = loadA8(r1p + 128);
    const bf16x8* WfH = (const bf16x8*)W1F + ((size_t)hk*32 + sl*4 + w)*64 + l;
    const bf16x8* WfL = WfH + 8*32*64;
    bf16x8 Bh = WfH[0], Bl = WfL[0];
    C1[0] = MFMA(Ah0, Bh, C1[0]); C1[1] = MFMA(Ah1, Bh, C1[1]);
    C1[0] = MFMA(Ah0, Bl, C1[0]); C1[1] = MFMA(Ah1, Bl, C1[1]);
    C1[0] = MFMA(Al0, Bh, C1[0]); C1[1] = MFMA(Al1, Bh, C1[1]);
  }
}

__device__ __forceinline__ void consumeSlice(int s, int w, int l, int quad, int r16,
    const ushort* buf, const ushort* __restrict__ W2F, f32x4 (&C2q)[8]){
  #pragma unroll
  for (int j2 = 0; j2 < 2; ++j2){
    int colBase = j2*32 + quad*8;
    bf16x8 Ah[2], Al[2];
    #pragma unroll
    for (int mtl = 0; mtl < 2; ++mtl){
      int m = mtl*16 + r16;
      Ah[mtl] = readA(buf, 0, m, colBase);
      Al[mtl] = readA(buf, 1, m, colBase);
    }
    const int kt = s*2 + j2;                       // W2 k-tile (KT=16)
    const bf16x8* WfH = (const bf16x8*)W2F + ((size_t)kt*16 + w*4)*64 + l;
    const bf16x8* WfL = WfH + 16*16*64;
    #pragma unroll
    for (int j = 0; j < 4; ++j){
      bf16x8 Bh = WfH[j*64], Bl = WfL[j*64];
      f32x4 c0 = C2q[j*2], c1 = C2q[j*2+1];
      c0 = MFMA(Ah[0], Bh, c0); c1 = MFMA(Ah[1], Bh, c1);
      c0 = MFMA(Ah[0], Bl, c0); c1 = MFMA(Ah[1], Bl, c1);
      c0 = MFMA(Al[0], Bh, c0); c1 = MFMA(Al[1], Bh, c1);
      C2q[j*2] = c0; C2q[j*2+1] = c1;
    }
  }
}

// ---------------------------------------------------------------------------
// kMLP R16: R15's K-half split redone with SLICE GROUPS OF 4 so the
// persistent C1 partial set is 32 regs (R15's 64 spilled: WRITE_SIZE 1.1 GB,
// VGPR fell to 64). Register peak ~ C1g(32)+C2q(32)+transients(~40) < 128.
// Per group: stage src rows -> hk0-3 x4 slices -> stage dst rows -> finish
// (hk4-7 + xpose + consume, dbuf'd). hk/kt order per accumulator unchanged
// -> bit-identical. LDS 35.8 KB -> 4 blocks/CU (16 waves, +33% TLP vs R13).
// A staged 4x/block (2 groups x src+dst) -- +32 KB/block coalesced, trivial.
// ---------------------------------------------------------------------------
__global__ __launch_bounds__(256, 4) void kMLP(
    const ushort* __restrict__ repsF,
    const ushort* __restrict__ W1F, const ushort* __restrict__ W2F,
    const ushort* __restrict__ W3F, const ushort* __restrict__ W4F,
    const float* __restrict__ b1, const float* __restrict__ b2,
    const float* __restrict__ b3, const float* __restrict__ b4,
    const float* __restrict__ W5, const float* __restrict__ b5,
    const int* __restrict__ edge_index, const int* __restrict__ batch,
    const int* __restrict__ y,
    float* __restrict__ scores, int* __restrict__ ebatch)
{
  __shared__ __align__(16) ushort sReg01[2*4352];  // regions 0,1 (17408 B)
  __shared__ __align__(16) ushort sA[2*4352];      // 32 A rows (8320 used);
                                                   // aliases regions 2,3 in L3
  __shared__ int sTy[32];
  __shared__ int sNode[64];
  __shared__ float sRed[4][32];

  const int tid = threadIdx.x;
  const int w = tid >> 6;                        // wave 0..3
  const int l = tid & 63;
  const int quad = l >> 4, r16 = l & 15;
  const int e0 = blockIdx.x * 32;

  if (tid < 32){
    int s = edge_index[e0 + tid];
    int d = edge_index[EE + e0 + tid];
    sNode[tid] = s;
    sNode[32 + tid] = d;
    int eb = batch[s];
    ebatch[e0 + tid] = eb;
    sTy[tid] = y[eb];
  }
  __syncthreads();

  // ---- layers 1+2 in 2 slice-groups of 4 (slices g*4 .. g*4+3) ----
  f32x4 C2q[8];                    // 4 local n-tiles x 2 m-tiles (32 regs)
  #pragma unroll
  for (int i=0;i<8;++i) C2q[i] = (f32x4)0.f;

  #pragma unroll
  for (int g = 0; g < 2; ++g){
    const int base = g*4;

    // stage SRC rows (32 x 512 B, coalesced)
    #pragma unroll
    for (int k = 0; k < 4; ++k){
      int c = tid + k*256;                       // 0..1023 16B-chunks
      int row = c >> 5, col = c & 31;
      const ushort* src = repsF + (size_t)sNode[row]*256 + col*8;
      uint4 v = *(const uint4*)src;
      ushort* dst = sA + row*AROW + col*8;
      *(uint2*)dst        = make_uint2(v.x, v.y);
      *(uint2*)(dst + 4)  = make_uint2(v.z, v.w);
    }
    __syncthreads();

    // pass 1: hk 0..3 (src K-half) for the 4 slices of this group
    f32x4 C1g[4][2];
    #pragma unroll
    for (int s4=0;s4<4;++s4){ C1g[s4][0] = (f32x4)0.f; C1g[s4][1] = (f32x4)0.f; }
    #pragma unroll
    for (int s4 = 0; s4 < 4; ++s4)
      produceHalf(base + s4, w, l, quad, r16, sA, 0, W1F, C1g[s4]);
    __syncthreads();   // all waves done reading src rows

    // restage DST rows over sA
    #pragma unroll
    for (int k = 0; k < 4; ++k){
      int c = tid + k*256;
      int row = c >> 5, col = c & 31;
      const ushort* src = repsF + (size_t)sNode[32 + row]*256 + col*8;
      uint4 v = *(const uint4*)src;
      ushort* dst = sA + row*AROW + col*8;
      *(uint2*)dst        = make_uint2(v.x, v.y);
      *(uint2*)(dst + 4)  = make_uint2(v.z, v.w);
    }
    __syncthreads();

    // pass 2: finish (hk 4..7) + xpose + consume, double-buffered
    produceHalf(base + 0, w, l, quad, r16, sA, 4, W1F, C1g[0]);
    xposeN<1>(sReg01 + w*16, C1g[0], b1 + base*64 + w*16, true, l);
    __syncthreads();
    #pragma unroll
    for (int s4 = 0; s4 < 3; ++s4){
      produceHalf(base + s4 + 1, w, l, quad, r16, sA, 4, W1F, C1g[s4+1]);
      xposeN<1>(sReg01 + ((s4+1)&1)*4352 + w*16, C1g[s4+1],
                b1 + (base+s4+1)*64 + w*16, true, l);
      consumeSlice(base + s4, w, l, quad, r16,
                   sReg01 + (s4&1)*4352, W2F, C2q);
      __syncthreads();
    }
    consumeSlice(base + 3, w, l, quad, r16, sReg01 + 4352, W2F, C2q);
    // no barrier here for g=0: next stage writes sA only (consume reads
    // regions); the stage's own trailing barrier orders everything.
  }
  __syncthreads();

  // ---- h2 staging: wave w -> region w (cols w*64..), elu+b2 ----
  // regions 2,3 alias sA (A dead after the slice loop).
  ushort* regW = (w < 2) ? (sReg01 + w*4352) : (sA + (w-2)*4352);
  xposeN<4>(regW, C2q, b2 + w*64, true, l);
  __syncthreads();

  // ---- layer 3: K=256 from h2 regions; wave w computes h3 cols w*32.. ----
  f32x4 C3q[4];
  #pragma unroll
  for (int i=0;i<4;++i) C3q[i] = (f32x4)0.f;
  #pragma unroll
  for (int kt = 0; kt < 8; ++kt){
    int rw = kt >> 1;
    const ushort* reg = (rw < 2) ? (sReg01 + rw*4352) : (sA + (rw-2)*4352);
    int colBase = (kt & 1)*32 + quad*8;
    bf16x8 Ah[2], Al[2];
    #pragma unroll
    for (int mtl = 0; mtl < 2; ++mtl){
      int m = mtl*16 + r16;
      Ah[mtl] = readA(reg, 0, m, colBase);
      Al[mtl] = readA(reg, 1, m, colBase);
    }
    const bf16x8* WfH = (const bf16x8*)W3F + ((size_t)kt*8 + w*2)*64 + l;
    const bf16x8* WfL = WfH + 8*8*64;
    #pragma unroll
    for (int j = 0; j < 2; ++j){
      bf16x8 Bh = WfH[j*64], Bl = WfL[j*64];
      f32x4 c0 = C3q[j*2], c1 = C3q[j*2+1];
      c0 = MFMA(Ah[0], Bh, c0); c1 = MFMA(Ah[1], Bh, c1);
      c0 = MFMA(Ah[0], Bl, c0); c1 = MFMA(Ah[1], Bl, c1);
      c0 = MFMA(Al[0], Bh, c0); c1 = MFMA(Al[1], Bh, c1);
      C3q[j*2] = c0; C3q[j*2+1] = c1;
    }
  }
  __syncthreads();   // all waves done reading h2 regions

  // ---- h3 staging (b3, NO elu): wave w -> region (w>>1), col (w&1)*32 ----
  xposeN<2>(sReg01 + (w>>1)*4352 + (w&1)*32, C3q, b3 + w*32, false, l);
  __syncthreads();

  // ---- layer 4: K=128 from h3 (regions 0-1); wave w -> h4 cols w*32.. ----
  f32x4 C4q[4];
  #pragma unroll
  for (int i=0;i<4;++i) C4q[i] = (f32x4)0.f;
  #pragma unroll
  for (int kt = 0; kt < 4; ++kt){
    const ushort* reg = sReg01 + (kt>>1)*4352;
    int colBase = (kt & 1)*32 + quad*8;
    bf16x8 Ah[2], Al[2];
    #pragma unroll
    for (int mtl = 0; mtl < 2; ++mtl){
      int m = mtl*16 + r16;
      Ah[mtl] = readA(reg, 0, m, colBase);
      Al[mtl] = readA(reg, 1, m, colBase);
    }
    const bf16x8* WfH = (const bf16x8*)W4F + ((size_t)kt*8 + w*2)*64 + l;
    const bf16x8* WfL = WfH + 4*8*64;
    #pragma unroll
    for (int j = 0; j < 2; ++j){
      bf16x8 Bh = WfH[j*64], Bl = WfL[j*64];
      f32x4 c0 = C4q[j*2], c1 = C4q[j*2+1];
      c0 = MFMA(Ah[0], Bh, c0); c1 = MFMA(Ah[1], Bh, c1);
      c0 = MFMA(Ah[0], Bl, c0); c1 = MFMA(Ah[1], Bl, c1);
      c0 = MFMA(Al[0], Bh, c0); c1 = MFMA(Al[1], Bh, c1);
      C4q[j*2] = c0; C4q[j*2+1] = c1;
    }
  }

  // ---- layer 5: per-wave partial dot over its 32 h4 cols, LDS reduce ----
  int tvals[2][4];
  #pragma unroll
  for (int mtl=0;mtl<2;++mtl)
    #pragma unroll
    for (int r=0;r<4;++r) tvals[mtl][r] = sTy[mtl*16 + quad*4 + r];

  float p[2][4] = {{0.f,0.f,0.f,0.f},{0.f,0.f,0.f,0.f}};
  #pragma unroll
  for (int j = 0; j < 2; ++j){
    int n4 = (w*2 + j)*16 + r16;
    float bv = b4[n4];
    const float* w5r = W5 + n4*LL;
    #pragma unroll
    for (int mtl = 0; mtl < 2; ++mtl){
      f32x4 c = C4q[j*2+mtl];
      #pragma unroll
      for (int r=0;r<4;++r)
        p[mtl][r] += elu_f(c[r] + bv) * w5r[tvals[mtl][r]];
    }
  }
  #pragma unroll
  for (int d = 8; d >= 1; d >>= 1){
    #pragma unroll
    for (int mtl=0;mtl<2;++mtl)
      #pragma unroll
      for (int r=0;r<4;++r)
        p[mtl][r] += __shfl_down(p[mtl][r], d, 16);
  }
  if (r16 == 0){
    #pragma unroll
    for (int mtl=0;mtl<2;++mtl)
      #pragma unroll
      for (int r=0;r<4;++r){
        int m = mtl*16 + quad*4 + r;
        sRed[w][m] = p[mtl][r];
      }
  }
  __syncthreads();
  if (tid < 32){
    float s = sRed[0][tid] + sRed[1][tid] + sRed[2][tid] + sRed[3][tid];
    scores[e0 + tid] = s + b5[sTy[tid]];
  }
}

// ---------------------------------------------------------------------------
// Segment softmax / argmax passes (unchanged, verified)
// ---------------------------------------------------------------------------
__global__ void kInitSeg(unsigned* segmax, float* segsum, unsigned* gmax, int* gact){
  int b = blockIdx.x*blockDim.x + threadIdx.x;
  if (b < BB){ segmax[b] = ENC_NEG_INF; segsum[b] = 0.f; gmax[b] = ENC_NEG_INF; gact[b] = 0x7FFFFFFF; }
}

__global__ __launch_bounds__(256) void kSegMax(const float* __restrict__ scores,
                                               const int* __restrict__ eb,
                                               unsigned* __restrict__ segmax){
  __shared__ unsigned l[BB];
  for (int b = threadIdx.x; b < BB; b += 256) l[b] = 0u;
  __syncthreads();
  for (int e = blockIdx.x*256 + threadIdx.x; e < EE; e += gridDim.x*256)
    atomicMax(&l[eb[e]], enc_f(scores[e]));
  __syncthreads();
  for (int b = threadIdx.x; b < BB; b += 256)
    if (l[b]) atomicMax(&segmax[b], l[b]);
}

__global__ __launch_bounds__(256) void kExpSum(const float* __restrict__ scores,
                                               const int* __restrict__ eb,
                                               const unsigned* __restrict__ segmax,
                                               float* __restrict__ segsum,
                                               float* __restrict__ outprobs){
  __shared__ float l[BB];
  for (int b = threadIdx.x; b < BB; b += 256) l[b] = 0.f;
  __syncthreads();
  for (int e = blockIdx.x*256 + threadIdx.x; e < EE; e += gridDim.x*256){
    int b = eb[e];
    float ex = expf(scores[e] - dec_f(segmax[b]));
    outprobs[e] = ex;
    atomicAdd(&l[b], ex);
  }
  __syncthreads();
  for (int b = threadIdx.x; b < BB; b += 256)
    if (l[b] != 0.f) atomicAdd(&segsum[b], l[b]);
}

__global__ __launch_bounds__(256) void kProbMax(float* __restrict__ outprobs,
                                                const int* __restrict__ eb,
                                                const float* __restrict__ segsum,
                                                unsigned* __restrict__ gmax){
  __shared__ unsigned l[BB];
  for (int b = threadIdx.x; b < BB; b += 256) l[b] = 0u;
  __syncthreads();
  for (int e = blockIdx.x*256 + threadIdx.x; e < EE; e += gridDim.x*256){
    int b = eb[e];
    float p = outprobs[e] / segsum[b];
    outprobs[e] = p;
    atomicMax(&l[b], enc_f(p));
  }
  __syncthreads();
  for (int b = threadIdx.x; b < BB; b += 256)
    if (l[b]) atomicMax(&gmax[b], l[b]);
}

__global__ __launch_bounds__(256) void kArgMin(const float* __restrict__ outprobs,
                                               const int* __restrict__ eb,
                                               const unsigned* __restrict__ gmax,
                                               int* __restrict__ gact){
  __shared__ int l[BB];
  for (int b = threadIdx.x; b < BB; b += 256) l[b] = 0x7FFFFFFF;
  __syncthreads();
  for (int e = blockIdx.x*256 + threadIdx.x; e < EE; e += gridDim.x*256){
    int b = eb[e];
    if (enc_f(outprobs[e]) == gmax[b]) atomicMin(&l[b], e);
  }
  __syncthreads();
  for (int b = threadIdx.x; b < BB; b += 256)
    if (l[b] != 0x7FFFFFFF) atomicMin(&gact[b], l[b]);
}

__global__ void kFinal(const unsigned* __restrict__ gmax, const int* __restrict__ gact,
                       float* __restrict__ out){
  int b = threadIdx.x;
  if (b < BB){
    out[EE + b]      = dec_f(gmax[b]);
    out[EE + BB + b] = (float)gact[b];
  }
}

// ---------------------------------------------------------------------------
extern "C" void kernel_launch(void* const* d_in, const int* in_sizes, int n_in,
                              void* d_out, int out_size, void* d_ws, size_t ws_size,
                              hipStream_t stream){
  const float* r0 = (const float*)d_in[0];
  const float* r1 = (const float*)d_in[1];
  const float* W1 = (const float*)d_in[2];
  const float* b1 = (const float*)d_in[3];
  const float* W2 = (const float*)d_in[4];
  const float* b2 = (const float*)d_in[5];
  const float* W3 = (const float*)d_in[6];
  const float* b3 = (const float*)d_in[7];
  const float* W4 = (const float*)d_in[8];
  const float* b4 = (const float*)d_in[9];
  const float* W5 = (const float*)d_in[10];
  const float* b5 = (const float*)d_in[11];
  const int* edge_index = (const int*)d_in[12];
  const int* batch = (const int*)d_in[13];
  const int* y = (const int*)d_in[14];
  float* out = (float*)d_out;

  char* ws = (char*)d_ws;
  size_t off = 0;
  float*    scores = (float*)(ws + off);    off += (size_t)EE*4;
  int*      ebatch = (int*)(ws + off);      off += (size_t)EE*4;
  unsigned* segmax = (unsigned*)(ws + off); off += BB*4;
  float*    segsum = (float*)(ws + off);    off += BB*4;
  unsigned* gmax   = (unsigned*)(ws + off); off += BB*4;
  int*      gact   = (int*)(ws + off);      off += BB*4;
  off = (off + 511) & ~(size_t)511;
  ushort* repsF = (ushort*)(ws + off);      off += (size_t)NN*256*2;   // 51.2 MB
  ushort* W1F   = (ushort*)(ws + off);      off += (size_t)2*8*32*512*2;
  ushort* W2F   = (ushort*)(ws + off);      off += (size_t)2*16*16*512*2;
  ushort* W3F   = (ushort*)(ws + off);      off += (size_t)2*8*8*512*2;
  ushort* W4F   = (ushort*)(ws + off);      off += (size_t)2*4*8*512*2;

  kInitSeg<<<2, 256, 0, stream>>>(segmax, segsum, gmax, gact);
  kReps<<<(NN*16)/256, 256, 0, stream>>>(r0, r1, repsF);
  kPrepW<<<(8*32*64)/256, 256, 0, stream>>>(W1, 512, 8, 32, W1F);
  kPrepW<<<(16*16*64)/256, 256, 0, stream>>>(W2, 256, 16, 16, W2F);
  kPrepW<<<(8*8*64)/256, 256, 0, stream>>>(W3, 128, 8, 8, W3F);
  kPrepW<<<(4*8*64)/256, 256, 0, stream>>>(W4, 128, 4, 8, W4F);

  kMLP<<<EE/32, 256, 0, stream>>>(repsF, W1F, W2F, W3F, W4F,
                                  b1, b2, b3, b4, W5, b5,
                                  edge_index, batch, y, scores, ebatch);

  kSegMax <<<256, 256, 0, stream>>>(scores, ebatch, segmax);
  kExpSum <<<256, 256, 0, stream>>>(scores, ebatch, segmax, segsum, out);
  kProbMax<<<256, 256, 0, stream>>>(out, ebatch, segsum, gmax);
  kArgMin <<<256, 256, 0, stream>>>(out, ebatch, gmax, gact);
  kFinal  <<<1, 512, 0, stream>>>(gmax, gact, out);
}

// Round 12
// 1417.894 us; speedup vs baseline: 1.1749x; 1.1127x over previous
//
#include <hip/hip_runtime.h>
#include <hip/hip_bf16.h>
#include <cmath>

#define NN 100000   // nodes
#define EE 600000   // edges
#define BB 512      // graphs
#define LL 10       // labels
// H=128; L1 256->512, L2 512->256, L3 256->128, L4 128->128, L5 128->10 (col-picked)

typedef __attribute__((ext_vector_type(8))) short  bf16x8;
typedef __attribute__((ext_vector_type(4))) float  f32x4;
typedef unsigned int uint;
typedef unsigned short ushort;
typedef unsigned long long u64;

// Fast elu (R13): __expf instead of libm expm1f; error ~2^-17, same order as
// the hi/lo bf16 representation. absmax tripwire >1e-3 => revert.
__device__ __forceinline__ float elu_f(float x){ return x > 0.f ? x : __expf(x) - 1.f; }

__device__ __forceinline__ ushort bf16_rne(float f){
  uint u = __float_as_uint(f);
  return (ushort)((u + 0x7FFFu + ((u >> 16) & 1u)) >> 16);
}

__device__ __forceinline__ f32x4 MFMA(bf16x8 a, bf16x8 b, f32x4 c){
  return __builtin_amdgcn_mfma_f32_16x16x32_bf16(a, b, c, 0, 0, 0);
}

// Monotone float<->uint encoding for atomic max/min on floats
__device__ __forceinline__ unsigned enc_f(float f){
  unsigned u = __float_as_uint(f);
  return (u & 0x80000000u) ? ~u : (u | 0x80000000u);
}
__device__ __forceinline__ float dec_f(unsigned u){
  return (u & 0x80000000u) ? __uint_as_float(u ^ 0x80000000u) : __uint_as_float(~u);
}
#define ENC_NEG_INF 0x007FFFFFu

// sA row stride (R13): 260 ushorts = 520 B -> 2-bank shift/row; conflict-free
// for the ds_read2_b64-lowered A-frag reads (every bank exactly 4 requests).
#define AROW 260

// ---------------------------------------------------------------------------
// kReps: repsF[n] = 512B row: [hi bf16 k=0..127][lo bf16 k=0..127].
// ---------------------------------------------------------------------------
__global__ __launch_bounds__(256) void kReps(const float* __restrict__ r0,
                                             const float* __restrict__ r1,
                                             ushort* __restrict__ repsF){
  int gid = blockIdx.x*256 + threadIdx.x;          // N*16 threads
  int n = gid >> 4, k8 = gid & 15;
  const float4* a = (const float4*)(r0 + (size_t)n*128 + k8*8);
  const float4* b = (const float4*)(r1 + (size_t)n*128 + k8*8);
  float4 x0 = a[0], x1 = a[1], y0 = b[0], y1 = b[1];
  float d[8] = {x0.x-y0.x, x0.y-y0.y, x0.z-y0.z, x0.w-y0.w,
                x1.x-y1.x, x1.y-y1.y, x1.z-y1.z, x1.w-y1.w};
  ushort hi[8], lo[8];
  #pragma unroll
  for (int j=0;j<8;++j){
    hi[j] = bf16_rne(d[j]);
    float fh = __uint_as_float(((uint)hi[j])<<16);
    lo[j] = bf16_rne(d[j] - fh);
  }
  ushort* dh = repsF + (size_t)n*256 + k8*8;
  ushort* dl = dh + 128;
  #pragma unroll
  for (int j=0;j<8;++j){ dh[j] = hi[j]; dl[j] = lo[j]; }
}

// ---------------------------------------------------------------------------
// kPrepW: weight [K][N] fp32 -> MFMA-fragment bf16 hi/lo:
//   dst[part][kt][nt][lane][j] with k = kt*32+(l>>4)*8+j, n = nt*16+(l&15).
// ---------------------------------------------------------------------------
__global__ __launch_bounds__(256) void kPrepW(const float* __restrict__ W, int N,
                                              int KT, int NT, ushort* __restrict__ dst){
  int gid = blockIdx.x*256 + threadIdx.x;
  int total = KT*NT*64;
  if (gid >= total) return;
  int l = gid & 63, tile = gid >> 6;
  int kt = tile / NT, nt = tile % NT;
  int kbase = kt*32 + (l>>4)*8;
  int n = nt*16 + (l&15);
  int partStride = KT*NT*512;
  int base = tile*512 + l*8;
  #pragma unroll
  for (int j=0;j<8;++j){
    float f = W[(size_t)(kbase+j)*N + n];
    ushort h = bf16_rne(f);
    float fh = __uint_as_float(((uint)h)<<16);
    dst[base + j] = h;
    dst[partStride + base + j] = bf16_rne(f - fh);
  }
}

// ---------------------------------------------------------------------------
// LDS transpose helpers (region = [part(2)][m(32)][col(64) pad 68] ushorts).
// Region = 4352 ushorts (8704 B); part offset 2176 ushorts = 1088 uints.
// ---------------------------------------------------------------------------
template<int NTILES>
__device__ __forceinline__ void xposeN(ushort* sT, const f32x4* Cg,
                                       const float* __restrict__ biasPtr,
                                       bool doElu, int l){
  const int quad = l >> 4, r16 = l & 15;
  uint* ldsu = (uint*)sT;
  #pragma unroll
  for (int i = 0; i < NTILES; ++i){
    float bv = biasPtr[i*16 + r16];
    #pragma unroll
    for (int mtl = 0; mtl < 2; ++mtl){
      f32x4 v = Cg[i*2 + mtl];
      ushort hi[4], lo[4];
      #pragma unroll
      for (int r = 0; r < 4; ++r){
        float f = v[r] + bv;
        if (doElu) f = elu_f(f);
        hi[r] = bf16_rne(f);
        float fh = __uint_as_float(((uint)hi[r]) << 16);
        lo[r] = bf16_rne(f - fh);
      }
      uint v01h = (uint)hi[0] | ((uint)hi[1]<<16);
      uint v23h = (uint)hi[2] | ((uint)hi[3]<<16);
      uint v01l = (uint)lo[0] | ((uint)lo[1]<<16);
      uint v23l = (uint)lo[2] | ((uint)lo[3]<<16);
      uint t01h = __shfl_xor(v01h,1), t23h = __shfl_xor(v23h,1);
      uint t01l = __shfl_xor(v01l,1), t23l = __shfl_xor(v23l,1);
      int c2 = (i*16 + (r16 & ~1)) >> 1;      // uint col index
      int m0 = mtl*16 + quad*4;
      if (!(l & 1)){
        ldsu[(m0+0)*34 + c2]        = (v01h & 0xFFFFu) | (t01h << 16);
        ldsu[(m0+1)*34 + c2]        = (v01h >> 16) | (t01h & 0xFFFF0000u);
        ldsu[1088 + (m0+0)*34 + c2] = (v01l & 0xFFFFu) | (t01l << 16);
        ldsu[1088 + (m0+1)*34 + c2] = (v01l >> 16) | (t01l & 0xFFFF0000u);
      } else {
        ldsu[(m0+2)*34 + c2]        = (t23h & 0xFFFFu) | (v23h << 16);
        ldsu[(m0+3)*34 + c2]        = (t23h >> 16) | (v23h & 0xFFFF0000u);
        ldsu[1088 + (m0+2)*34 + c2] = (t23l & 0xFFFFu) | (v23l << 16);
        ldsu[1088 + (m0+3)*34 + c2] = (t23l >> 16) | (v23l & 0xFFFF0000u);
      }
    }
  }
}

__device__ __forceinline__ bf16x8 readA(const ushort* region, int part, int m, int colBase){
  union { uint2 u[2]; bf16x8 v; } cvt;
  const ushort* p = region + part*2176 + m*68 + colBase;
  cvt.u[0] = *(const uint2*)p;
  cvt.u[1] = *(const uint2*)(p + 4);
  return cvt.v;
}

// 8B-aligned bf16x8 load from sA (row stride 520 B: odd rows only 8B-aligned).
__device__ __forceinline__ bf16x8 loadA8(const ushort* p){
  union { uint2 u[2]; bf16x8 v; } cvt;
  cvt.u[0] = *(const uint2*)p;
  cvt.u[1] = *(const uint2*)(p + 4);
  return cvt.v;
}

// ---------------------------------------------------------------------------
// R12/R13 structure: 4-wave N-split + A staged in LDS once per block.
// produceSlice: wave w computes n-tile (s*4+w) of h1 from LDS-A.
// consumeSlice: h2 accumulate, strided n-tiles (j*4+w).
// ---------------------------------------------------------------------------
__device__ __forceinline__ void produceSlice(int s, int w, int l, int quad, int r16,
    const ushort* sA,
    const ushort* __restrict__ W1F, const float* __restrict__ b1,
    ushort* buf){
  f32x4 C1[2];
  C1[0] = (f32x4)0.f; C1[1] = (f32x4)0.f;
  #pragma unroll
  for (int hk = 0; hk < 8; ++hk){  // K=256: src k-tiles 0..3, dst 4..7
    const int rbase = (hk < 4) ? 0 : 32;
    const int ko = (hk & 3)*32 + quad*8;
    const ushort* r0p = sA + (rbase + r16)*AROW + ko;
    const ushort* r1p = sA + (rbase + 16 + r16)*AROW + ko;
    bf16x8 Ah0 = loadA8(r0p);
    bf16x8 Al0 = loadA8(r0p + 128);
    bf16x8 Ah1 = loadA8(r1p);
    bf16x8 Al1 = loadA8(r1p + 128);
    const bf16x8* WfH = (const bf16x8*)W1F + ((size_t)hk*32 + s*4 + w)*64 + l;
    const bf16x8* WfL = WfH + 8*32*64;
    bf16x8 Bh = WfH[0], Bl = WfL[0];
    C1[0] = MFMA(Ah0, Bh, C1[0]); C1[1] = MFMA(Ah1, Bh, C1[1]);
    C1[0] = MFMA(Ah0, Bl, C1[0]); C1[1] = MFMA(Ah1, Bl, C1[1]);
    C1[0] = MFMA(Al0, Bh, C1[0]); C1[1] = MFMA(Al1, Bh, C1[1]);
  }
  // n-tile -> slice buffer at col offset w*16 (16 ushorts, uint-aligned)
  xposeN<1>(buf + w*16, C1, b1 + s*64 + w*16, true, l);
}

__device__ __forceinline__ void consumeSlice(int s, int w, int l, int quad, int r16,
    const ushort* buf, const ushort* __restrict__ W2F, f32x4 (&C2q)[8]){
  #pragma unroll
  for (int j2 = 0; j2 < 2; ++j2){
    int colBase = j2*32 + quad*8;
    bf16x8 Ah[2], Al[2];
    #pragma unroll
    for (int mtl = 0; mtl < 2; ++mtl){
      int m = mtl*16 + r16;
      Ah[mtl] = readA(buf, 0, m, colBase);
      Al[mtl] = readA(buf, 1, m, colBase);
    }
    const int kt = s*2 + j2;                       // W2 k-tile (KT=16)
    const bf16x8* WfH = (const bf16x8*)W2F + ((size_t)kt*16 + w*4)*64 + l;
    const bf16x8* WfL = WfH + 16*16*64;
    #pragma unroll
    for (int j = 0; j < 4; ++j){
      bf16x8 Bh = WfH[j*64], Bl = WfL[j*64];
      f32x4 c0 = C2q[j*2], c1 = C2q[j*2+1];
      c0 = MFMA(Ah[0], Bh, c0); c1 = MFMA(Ah[1], Bh, c1);
      c0 = MFMA(Ah[0], Bl, c0); c1 = MFMA(Ah[1], Bl, c1);
      c0 = MFMA(Al[0], Bh, c0); c1 = MFMA(Al[1], Bh, c1);
      C2q[j*2] = c0; C2q[j*2+1] = c1;
    }
  }
}

// ---------------------------------------------------------------------------
// kMLP R17: exact R13 structure (verified 1430 us; R14/15/16 reverted) with
// __launch_bounds__(256,3). LDS (51.7 KB) already caps occupancy at 3
// blocks/CU, so (256,4)'s 128-VGPR cap was a pure constraint with no
// occupancy benefit; (256,3) raises the cap to ~168 and lets the scheduler
// hoist more loads WITHIN the existing structure (no source pipelining --
// that's what R14 proved counterproductive).
// ---------------------------------------------------------------------------
__global__ __launch_bounds__(256, 3) void kMLP(
    const ushort* __restrict__ repsF,
    const ushort* __restrict__ W1F, const ushort* __restrict__ W2F,
    const ushort* __restrict__ W3F, const ushort* __restrict__ W4F,
    const float* __restrict__ b1, const float* __restrict__ b2,
    const float* __restrict__ b3, const float* __restrict__ b4,
    const float* __restrict__ W5, const float* __restrict__ b5,
    const int* __restrict__ edge_index, const int* __restrict__ batch,
    const int* __restrict__ y,
    float* __restrict__ scores, int* __restrict__ ebatch)
{
  __shared__ __align__(16) ushort sReg01[2*4352];  // regions 0,1
  __shared__ __align__(16) ushort sA[64*AROW];     // A rows; aliases regions 2,3
  __shared__ int sTy[32];
  __shared__ int sNode[64];
  __shared__ float sRed[4][32];

  const int tid = threadIdx.x;
  const int w = tid >> 6;                        // wave 0..3
  const int l = tid & 63;
  const int quad = l >> 4, r16 = l & 15;
  const int e0 = blockIdx.x * 32;

  if (tid < 32){
    int s = edge_index[e0 + tid];
    int d = edge_index[EE + e0 + tid];
    sNode[tid] = s;
    sNode[32 + tid] = d;
    int eb = batch[s];
    ebatch[e0 + tid] = eb;
    sTy[tid] = y[eb];
  }
  __syncthreads();

  // ---- one-shot coalesced A gather: 64 rows x 512 B -> sA ----
  #pragma unroll
  for (int k = 0; k < 8; ++k){
    int c = tid + k*256;                         // 0..2047 16B-chunks
    int row = c >> 5, col = c & 31;              // 32 chunks per row
    const ushort* src = repsF + (size_t)sNode[row]*256 + col*8;
    uint4 v = *(const uint4*)src;
    ushort* dst = sA + row*AROW + col*8;
    *(uint2*)dst        = make_uint2(v.x, v.y);
    *(uint2*)(dst + 4)  = make_uint2(v.z, v.w);
  }
  __syncthreads();

  // ---- layers 1+2: h1 (N=512) in 8 slices of 64 cols; C2q accumulates ----
  f32x4 C2q[8];                    // 4 local n-tiles x 2 m-tiles (32 regs)
  #pragma unroll
  for (int i=0;i<8;++i) C2q[i] = (f32x4)0.f;

  produceSlice(0, w, l, quad, r16, sA, W1F, b1, sReg01);
  __syncthreads();
  #pragma unroll 1
  for (int s = 0; s < 7; ++s){
    produceSlice(s+1, w, l, quad, r16, sA, W1F, b1, sReg01 + ((s+1)&1)*4352);
    consumeSlice(s, w, l, quad, r16, sReg01 + (s&1)*4352, W2F, C2q);
    __syncthreads();
  }
  consumeSlice(7, w, l, quad, r16, sReg01 + 4352, W2F, C2q);
  __syncthreads();

  // ---- h2 staging: wave w -> region w (cols w*64..), elu+b2 ----
  // regions 2,3 alias sA (A dead after the slice loop).
  ushort* regW = (w < 2) ? (sReg01 + w*4352) : (sA + (w-2)*4352);
  xposeN<4>(regW, C2q, b2 + w*64, true, l);
  __syncthreads();

  // ---- layer 3: K=256 from h2 regions; wave w computes h3 cols w*32.. ----
  f32x4 C3q[4];
  #pragma unroll
  for (int i=0;i<4;++i) C3q[i] = (f32x4)0.f;
  #pragma unroll
  for (int kt = 0; kt < 8; ++kt){
    int rw = kt >> 1;
    const ushort* reg = (rw < 2) ? (sReg01 + rw*4352) : (sA + (rw-2)*4352);
    int colBase = (kt & 1)*32 + quad*8;
    bf16x8 Ah[2], Al[2];
    #pragma unroll
    for (int mtl = 0; mtl < 2; ++mtl){
      int m = mtl*16 + r16;
      Ah[mtl] = readA(reg, 0, m, colBase);
      Al[mtl] = readA(reg, 1, m, colBase);
    }
    const bf16x8* WfH = (const bf16x8*)W3F + ((size_t)kt*8 + w*2)*64 + l;
    const bf16x8* WfL = WfH + 8*8*64;
    #pragma unroll
    for (int j = 0; j < 2; ++j){
      bf16x8 Bh = WfH[j*64], Bl = WfL[j*64];
      f32x4 c0 = C3q[j*2], c1 = C3q[j*2+1];
      c0 = MFMA(Ah[0], Bh, c0); c1 = MFMA(Ah[1], Bh, c1);
      c0 = MFMA(Ah[0], Bl, c0); c1 = MFMA(Ah[1], Bl, c1);
      c0 = MFMA(Al[0], Bh, c0); c1 = MFMA(Al[1], Bh, c1);
      C3q[j*2] = c0; C3q[j*2+1] = c1;
    }
  }
  __syncthreads();   // all waves done reading h2 regions

  // ---- h3 staging (b3, NO elu): wave w -> region (w>>1), col (w&1)*32 ----
  xposeN<2>(sReg01 + (w>>1)*4352 + (w&1)*32, C3q, b3 + w*32, false, l);
  __syncthreads();

  // ---- layer 4: K=128 from h3 (regions 0-1); wave w -> h4 cols w*32.. ----
  f32x4 C4q[4];
  #pragma unroll
  for (int i=0;i<4;++i) C4q[i] = (f32x4)0.f;
  #pragma unroll
  for (int kt = 0; kt < 4; ++kt){
    const ushort* reg = sReg01 + (kt>>1)*4352;
    int colBase = (kt & 1)*32 + quad*8;
    bf16x8 Ah[2], Al[2];
    #pragma unroll
    for (int mtl = 0; mtl < 2; ++mtl){
      int m = mtl*16 + r16;
      Ah[mtl] = readA(reg, 0, m, colBase);
      Al[mtl] = readA(reg, 1, m, colBase);
    }
    const bf16x8* WfH = (const bf16x8*)W4F + ((size_t)kt*8 + w*2)*64 + l;
    const bf16x8* WfL = WfH + 4*8*64;
    #pragma unroll
    for (int j = 0; j < 2; ++j){
      bf16x8 Bh = WfH[j*64], Bl = WfL[j*64];
      f32x4 c0 = C4q[j*2], c1 = C4q[j*2+1];
      c0 = MFMA(Ah[0], Bh, c0); c1 = MFMA(Ah[1], Bh, c1);
      c0 = MFMA(Ah[0], Bl, c0); c1 = MFMA(Ah[1], Bl, c1);
      c0 = MFMA(Al[0], Bh, c0); c1 = MFMA(Al[1], Bh, c1);
      C4q[j*2] = c0; C4q[j*2+1] = c1;
    }
  }

  // ---- layer 5: per-wave partial dot over its 32 h4 cols, LDS reduce ----
  int tvals[2][4];
  #pragma unroll
  for (int mtl=0;mtl<2;++mtl)
    #pragma unroll
    for (int r=0;r<4;++r) tvals[mtl][r] = sTy[mtl*16 + quad*4 + r];

  float p[2][4] = {{0.f,0.f,0.f,0.f},{0.f,0.f,0.f,0.f}};
  #pragma unroll
  for (int j = 0; j < 2; ++j){
    int n4 = (w*2 + j)*16 + r16;
    float bv = b4[n4];
    const float* w5r = W5 + n4*LL;
    #pragma unroll
    for (int mtl = 0; mtl < 2; ++mtl){
      f32x4 c = C4q[j*2+mtl];
      #pragma unroll
      for (int r=0;r<4;++r)
        p[mtl][r] += elu_f(c[r] + bv) * w5r[tvals[mtl][r]];
    }
  }
  #pragma unroll
  for (int d = 8; d >= 1; d >>= 1){
    #pragma unroll
    for (int mtl=0;mtl<2;++mtl)
      #pragma unroll
      for (int r=0;r<4;++r)
        p[mtl][r] += __shfl_down(p[mtl][r], d, 16);
  }
  if (r16 == 0){
    #pragma unroll
    for (int mtl=0;mtl<2;++mtl)
      #pragma unroll
      for (int r=0;r<4;++r){
        int m = mtl*16 + quad*4 + r;
        sRed[w][m] = p[mtl][r];
      }
  }
  __syncthreads();
  if (tid < 32){
    float s = sRed[0][tid] + sRed[1][tid] + sRed[2][tid] + sRed[3][tid];
    scores[e0 + tid] = s + b5[sTy[tid]];
  }
}

// ---------------------------------------------------------------------------
// Segment softmax / argmax passes.
// R17: kProbMax+kArgMin fused into kMaxArg via packed u64 atomicMin on
// key = (~enc(prob) << 32) | edge_idx  -> max prob, tie-break min index
// (lexicographic; identical float comparison to reference semantics).
// ---------------------------------------------------------------------------
__global__ void kInitSeg(unsigned* segmax, float* segsum, u64* gkey){
  int b = blockIdx.x*blockDim.x + threadIdx.x;
  if (b < BB){ segmax[b] = ENC_NEG_INF; segsum[b] = 0.f; gkey[b] = ~0ull; }
}

__global__ __launch_bounds__(256) void kSegMax(const float* __restrict__ scores,
                                               const int* __restrict__ eb,
                                               unsigned* __restrict__ segmax){
  __shared__ unsigned l[BB];
  for (int b = threadIdx.x; b < BB; b += 256) l[b] = 0u;
  __syncthreads();
  for (int e = blockIdx.x*256 + threadIdx.x; e < EE; e += gridDim.x*256)
    atomicMax(&l[eb[e]], enc_f(scores[e]));
  __syncthreads();
  for (int b = threadIdx.x; b < BB; b += 256)
    if (l[b]) atomicMax(&segmax[b], l[b]);
}

__global__ __launch_bounds__(256) void kExpSum(const float* __restrict__ scores,
                                               const int* __restrict__ eb,
                                               const unsigned* __restrict__ segmax,
                                               float* __restrict__ segsum,
                                               float* __restrict__ outprobs){
  __shared__ float l[BB];
  for (int b = threadIdx.x; b < BB; b += 256) l[b] = 0.f;
  __syncthreads();
  for (int e = blockIdx.x*256 + threadIdx.x; e < EE; e += gridDim.x*256){
    int b = eb[e];
    float ex = expf(scores[e] - dec_f(segmax[b]));
    outprobs[e] = ex;
    atomicAdd(&l[b], ex);
  }
  __syncthreads();
  for (int b = threadIdx.x; b < BB; b += 256)
    if (l[b] != 0.f) atomicAdd(&segsum[b], l[b]);
}

__global__ __launch_bounds__(256) void kMaxArg(float* __restrict__ outprobs,
                                               const int* __restrict__ eb,
                                               const float* __restrict__ segsum,
                                               u64* __restrict__ gkey){
  __shared__ u64 l[BB];
  for (int b = threadIdx.x; b < BB; b += 256) l[b] = ~0ull;
  __syncthreads();
  for (int e = blockIdx.x*256 + threadIdx.x; e < EE; e += gridDim.x*256){
    int b = eb[e];
    float p = outprobs[e] / segsum[b];
    outprobs[e] = p;
    u64 key = ((u64)(~enc_f(p)) << 32) | (unsigned)e;
    atomicMin(&l[b], key);
  }
  __syncthreads();
  for (int b = threadIdx.x; b < BB; b += 256)
    if (l[b] != ~0ull) atomicMin(&gkey[b], l[b]);
}

__global__ void kFinal(const u64* __restrict__ gkey, float* __restrict__ out){
  int b = threadIdx.x;
  if (b < BB){
    u64 k = gkey[b];
    unsigned enc = ~(unsigned)(k >> 32);
    out[EE + b]      = dec_f(enc);
    out[EE + BB + b] = (float)(unsigned)(k & 0xFFFFFFFFu);
  }
}

// ---------------------------------------------------------------------------
extern "C" void kernel_launch(void* const* d_in, const int* in_sizes, int n_in,
                              void* d_out, int out_size, void* d_ws, size_t ws_size,
                              hipStream_t stream){
  const float* r0 = (const float*)d_in[0];
  const float* r1 = (const float*)d_in[1];
  const float* W1 = (const float*)d_in[2];
  const float* b1 = (const float*)d_in[3];
  const float* W2 = (const float*)d_in[4];
  const float* b2 = (const float*)d_in[5];
  const float* W3 = (const float*)d_in[6];
  const float* b3 = (const float*)d_in[7];
  const float* W4 = (const float*)d_in[8];
  const float* b4 = (const float*)d_in[9];
  const float* W5 = (const float*)d_in[10];
  const float* b5 = (const float*)d_in[11];
  const int* edge_index = (const int*)d_in[12];
  const int* batch = (const int*)d_in[13];
  const int* y = (const int*)d_in[14];
  float* out = (float*)d_out;

  char* ws = (char*)d_ws;
  size_t off = 0;
  float*    scores = (float*)(ws + off);    off += (size_t)EE*4;
  int*      ebatch = (int*)(ws + off);      off += (size_t)EE*4;
  unsigned* segmax = (unsigned*)(ws + off); off += BB*4;
  float*    segsum = (float*)(ws + off);    off += BB*4;
  off = (off + 7) & ~(size_t)7;
  u64*      gkey   = (u64*)(ws + off);      off += BB*8;
  off = (off + 511) & ~(size_t)511;
  ushort* repsF = (ushort*)(ws + off);      off += (size_t)NN*256*2;   // 51.2 MB
  ushort* W1F   = (ushort*)(ws + off);      off += (size_t)2*8*32*512*2;
  ushort* W2F   = (ushort*)(ws + off);      off += (size_t)2*16*16*512*2;
  ushort* W3F   = (ushort*)(ws + off);      off += (size_t)2*8*8*512*2;
  ushort* W4F   = (ushort*)(ws + off);      off += (size_t)2*4*8*512*2;

  kInitSeg<<<2, 256, 0, stream>>>(segmax, segsum, gkey);
  kReps<<<(NN*16)/256, 256, 0, stream>>>(r0, r1, repsF);
  kPrepW<<<(8*32*64)/256, 256, 0, stream>>>(W1, 512, 8, 32, W1F);
  kPrepW<<<(16*16*64)/256, 256, 0, stream>>>(W2, 256, 16, 16, W2F);
  kPrepW<<<(8*8*64)/256, 256, 0, stream>>>(W3, 128, 8, 8, W3F);
  kPrepW<<<(4*8*64)/256, 256, 0, stream>>>(W4, 128, 4, 8, W4F);

  kMLP<<<EE/32, 256, 0, stream>>>(repsF, W1F, W2F, W3F, W4F,
                                  b1, b2, b3, b4, W5, b5,
                                  edge_index, batch, y, scores, ebatch);

  kSegMax<<<256, 256, 0, stream>>>(scores, ebatch, segmax);
  kExpSum<<<256, 256, 0, stream>>>(scores, ebatch, segmax, segsum, out);
  kMaxArg<<<256, 256, 0, stream>>>(out, ebatch, segsum, gkey);
  kFinal <<<1, 512, 0, stream>>>(gkey, out);
}